// Round 3
// baseline (442.628 us; speedup 1.0000x reference)
//
#include <hip/hip_runtime.h>
#include <math.h>
#include <stdint.h>

#define N_NODE 1024
#define NC 128            // b*d = 64*2
#define T_ALL 12
#define T1 11
#define NP 24             // period / number of graphs
#define NN (N_NODE*N_NODE)   // 1048576
#define HJ 72             // 3*H
#define HH 24             // H

// ---- workspace layout (float offsets for legacy part) ----
#define WS_SC     0                                   // 12*1024*128 = 1572864
#define WS_COV    (WS_SC + T_ALL*N_NODE*NC)           // + 1048576
#define WS_MPART  (WS_COV + NN)                       // + 11*24*8 = 2112
#define WS_IDX    (WS_MPART + T1*NP*8)                // + 16 (ints)
#define WS_MEAN   (WS_IDX + 16)                       // + 1024
#define WS_GIPART (WS_MEAN + N_NODE)                  // + 128*72*12 = 110592
#define WS_GI     (WS_GIPART + 128*HJ*T_ALL)          // + 864
#define WS_BASE_FLOATS (WS_GI + HJ*T_ALL)             // = 2736064

// byte offsets for bf16 hi/lo tile arrays
#define AB_BASE_BYTES ((size_t)WS_BASE_FLOATS * 4)    // 10944256, 16B aligned
#define AHI_BYTES ((size_t)24*1024*1024*2)            // 50331648
#define BHI_BYTES ((size_t)11*32*4096*2)              // 2883584
#define WS_NEED_BYTES (AB_BASE_BYTES + 2*AHI_BYTES + 2*BHI_BYTES)  // 117374720

typedef __attribute__((ext_vector_type(8))) short short8v;
typedef __attribute__((ext_vector_type(8))) unsigned short ushort8v;
typedef __attribute__((ext_vector_type(4))) float f32x4;

// ---------------------------------------------------------------------------
__device__ __forceinline__ void gload16(const void* g, void* l) {
    __builtin_amdgcn_global_load_lds(
        (const __attribute__((address_space(1))) uint32_t*)g,
        (__attribute__((address_space(3))) uint32_t*)l, 16, 0, 0);
}

__device__ __forceinline__ void cvt_hilo(float f, unsigned short& h, unsigned short& l) {
    union { float f; uint32_t u; } a; a.f = f;
    uint32_t r = a.u + 0x7FFFu + ((a.u >> 16) & 1u);
    h = (unsigned short)(r >> 16);
    union { uint32_t u; float f; } hb; hb.u = ((uint32_t)h) << 16;
    float lo = f - hb.f;
    union { float f; uint32_t u; } b; b.f = lo;
    uint32_t r2 = b.u + 0x7FFFu + ((b.u >> 16) & 1u);
    l = (unsigned short)(r2 >> 16);
}

// ---------------------------------------------------------------------------
// K1: sc[t][n][c] = inputs[b][n][t*2+dd], c = 2b+dd.
// LDS-tiled transpose: coalesced 24-float-run reads, coalesced 32-float writes.
// grid 128 blocks = 4 b-tiles(16) x 32 n-tiles(32).
__global__ __launch_bounds__(256) void k_build_sc(const float* __restrict__ inp,
                                                  float* __restrict__ sc) {
    __shared__ float ld[12830];   // addr(n,b,td) = n*401 + b*25 + td
    int b0 = (blockIdx.x & 3) * 16;
    int n0 = (blockIdx.x >> 2) * 32;
    for (int idx = threadIdx.x; idx < 3072; idx += 256) {
        int bb = idx / 192;            // 0..15
        int rem = idx - bb * 192;
        int nn = rem / 6;              // 0..31
        int q  = rem - nn * 6;         // 0..5
        const float4 v = *(const float4*)(inp +
            ((size_t)(b0 + bb) * 1024 + (n0 + nn)) * 24 + q * 4);
        int base = nn * 401 + bb * 25 + q * 4;
        ld[base + 0] = v.x; ld[base + 1] = v.y;
        ld[base + 2] = v.z; ld[base + 3] = v.w;
    }
    __syncthreads();
    for (int idx = threadIdx.x; idx < 12288; idx += 256) {
        int t = idx >> 10;
        int rem = idx & 1023;
        int nn = rem >> 5, cc = rem & 31;
        int bb = cc >> 1, dd = cc & 1;
        sc[(size_t)t * 131072 + (size_t)(n0 + nn) * 128 + b0 * 2 + cc] =
            ld[nn * 401 + bb * 25 + t * 2 + dd];
    }
}

// ---------------------------------------------------------------------------
// Convert graphs -> tile-contiguous, XOR-swizzled bf16 hi/lo images.
// Tile (p,nt,ks) = G[p][nt*128..+128][ks*32..+32] stored as 4096 ushort:
//   byte_off(r,kk) = (r*64 + kk*2) ^ ((r&7)<<4)
__global__ __launch_bounds__(256) void k_cvt_A(const float* __restrict__ G,
                                               unsigned short* __restrict__ Ahi,
                                               unsigned short* __restrict__ Alo) {
    int tile = blockIdx.x;            // 0..6143 = (p*8+nt)*32+ks
    int ks = tile & 31;
    int pn = tile >> 5;
    int nt = pn & 7, p = pn >> 3;
    const float* Gt = G + (size_t)p * NN + (size_t)(nt * 128) * 1024 + ks * 32;
    size_t base = (size_t)tile * 4096;
#pragma unroll
    for (int g2 = 0; g2 < 2; ++g2) {
        int gid = threadIdx.x * 2 + g2;   // 0..511
        int r = gid >> 2, gg = gid & 3;
        const float* src = Gt + (size_t)r * 1024 + gg * 8;
        ushort8v h, l;
#pragma unroll
        for (int j = 0; j < 8; ++j) {
            unsigned short hh, ll;
            cvt_hilo(src[j], hh, ll);
            h[j] = hh; l[j] = ll;
        }
        int offu = ((r * 64 + gg * 16) ^ ((r & 7) << 4)) >> 1;  // ushort index
        *(ushort8v*)(Ahi + base + offu) = h;
        *(ushort8v*)(Alo + base + offu) = l;
    }
}

// Convert sc[t] (t<11) -> transposed [c][kk] swizzled bf16 tiles.
// Tile (t,ks): element (c,kk) = sc[t][ks*32+kk][c]; byte_off = (c*64+kk*2)^((c&7)<<4)
__global__ __launch_bounds__(256) void k_cvt_B(const float* __restrict__ sc,
                                               unsigned short* __restrict__ Bhi,
                                               unsigned short* __restrict__ Blo) {
    __shared__ float s[32][129];
    int tile = blockIdx.x;            // 0..351 = t*32+ks
    int ks = tile & 31;
    int t = tile >> 5;
    const float* S = sc + (size_t)t * (N_NODE * NC) + (size_t)ks * 32 * 128;
#pragma unroll
    for (int i = 0; i < 4; ++i) {
        int fi = threadIdx.x + i * 256;      // float4 index 0..1023
        int m = fi >> 5, c4 = fi & 31;
        float4 v = *(const float4*)(S + (size_t)m * 128 + c4 * 4);
        s[m][c4 * 4 + 0] = v.x;
        s[m][c4 * 4 + 1] = v.y;
        s[m][c4 * 4 + 2] = v.z;
        s[m][c4 * 4 + 3] = v.w;
    }
    __syncthreads();
    size_t base = (size_t)tile * 4096;
#pragma unroll
    for (int g2 = 0; g2 < 2; ++g2) {
        int gid = threadIdx.x * 2 + g2;   // 0..511
        int c = gid >> 2, gg = gid & 3;
        ushort8v h, l;
#pragma unroll
        for (int j = 0; j < 8; ++j) {
            unsigned short hh, ll;
            cvt_hilo(s[gg * 8 + j][c], hh, ll);
            h[j] = hh; l[j] = ll;
        }
        int offu = ((c * 64 + gg * 16) ^ ((c & 7) << 4)) >> 1;
        *(ushort8v*)(Bhi + base + offu) = h;
        *(ushort8v*)(Blo + base + offu) = l;
    }
}

// ---------------------------------------------------------------------------
// K2 (MFMA): bf16x3 GEMM + masked abs-diff reduce.
// 1-D grid 2112, XCD-chunked swizzle, t fastest (11 consecutive blocks share
// one A-panel -> same-XCD L2 hits). Double-buffered LDS, prefetch-ahead-1,
// one barrier per k-step, setprio around MFMA cluster.
__global__ __launch_bounds__(256) void k_metrics_mfma(
        const unsigned short* __restrict__ Ahi, const unsigned short* __restrict__ Alo,
        const unsigned short* __restrict__ Bhi, const unsigned short* __restrict__ Blo,
        const float* __restrict__ sc, float* __restrict__ mpart) {
    __shared__ unsigned short lds[2][4][4096];   // 2 x {A_hi,A_lo,B_hi,B_lo} x 8KB
    __shared__ float red[256];

    int bid = blockIdx.x;                      // 0..2111
    int orig = (bid & 7) * 264 + (bid >> 3);   // chunked XCD swizzle (2112 = 8*264)
    int t = orig % 11;
    int pn = orig / 11;                        // 0..191
    int nt = pn & 7, p = pn >> 3;

    int tid = threadIdx.x;
    int lane = tid & 63, wv = tid >> 6;
    int wr = wv >> 1, wc = wv & 1;
    int lr = lane & 15, lg = lane >> 4;

    size_t abase = (size_t)(p * 8 + nt) * 32 * 4096;
    size_t bbase = (size_t)t * 32 * 4096;
    const unsigned short* srcs = (wv == 0) ? Ahi + abase
                               : (wv == 1) ? Alo + abase
                               : (wv == 2) ? Bhi + bbase
                                           : Blo + bbase;

    f32x4 acc[4][4];
#pragma unroll
    for (int m = 0; m < 4; ++m)
#pragma unroll
        for (int n = 0; n < 4; ++n)
            acc[m][n] = (f32x4){0.f, 0.f, 0.f, 0.f};

    int aoff[4], boff[4];
#pragma unroll
    for (int m = 0; m < 4; ++m) {
        int row = wr * 64 + m * 16 + lr;
        aoff[m] = (row * 64 + lg * 16) ^ ((row & 7) << 4);
    }
#pragma unroll
    for (int n = 0; n < 4; ++n) {
        int col = wc * 64 + n * 16 + lr;
        boff[n] = (col * 64 + lg * 16) ^ ((col & 7) << 4);
    }

    // prologue: stage k-step 0 into buffer 0
    {
        const unsigned short* sp = srcs;
        unsigned short* lb = &lds[0][wv][0];
#pragma unroll
        for (int i = 0; i < 8; ++i)
            gload16(sp + i * 512 + lane * 8, lb + i * 512);
    }
    __syncthreads();   // drains vmcnt -> buf0 ready

    for (int ks = 0; ks < 32; ++ks) {
        int cur = ks & 1;
        // issue next-tile staging BEFORE compute (latency hides under MFMA)
        if (ks < 31) {
            const unsigned short* sp = srcs + (size_t)(ks + 1) * 4096;
            unsigned short* lb = &lds[cur ^ 1][wv][0];
#pragma unroll
            for (int i = 0; i < 8; ++i)
                gload16(sp + i * 512 + lane * 8, lb + i * 512);
        }
        const char* L0 = (const char*)&lds[cur][0][0];
        const char* L1 = (const char*)&lds[cur][1][0];
        const char* L2 = (const char*)&lds[cur][2][0];
        const char* L3 = (const char*)&lds[cur][3][0];

        short8v ah[4], al[4], bh[4], bl[4];
#pragma unroll
        for (int m = 0; m < 4; ++m) {
            ah[m] = *(const short8v*)(L0 + aoff[m]);
            al[m] = *(const short8v*)(L1 + aoff[m]);
        }
#pragma unroll
        for (int n = 0; n < 4; ++n) {
            bh[n] = *(const short8v*)(L2 + boff[n]);
            bl[n] = *(const short8v*)(L3 + boff[n]);
        }
        __builtin_amdgcn_s_setprio(1);
#pragma unroll
        for (int m = 0; m < 4; ++m)
#pragma unroll
            for (int n = 0; n < 4; ++n) {
                acc[m][n] = __builtin_amdgcn_mfma_f32_16x16x32_bf16(ah[m], bh[n], acc[m][n], 0, 0, 0);
                acc[m][n] = __builtin_amdgcn_mfma_f32_16x16x32_bf16(ah[m], bl[n], acc[m][n], 0, 0, 0);
                acc[m][n] = __builtin_amdgcn_mfma_f32_16x16x32_bf16(al[m], bh[n], acc[m][n], 0, 0, 0);
            }
        __builtin_amdgcn_s_setprio(0);
        __syncthreads();   // drains vmcnt (next buf staged) + syncs buffer swap
    }

    // epilogue: masked |pred - target| partial sum
    // C/D layout: col = lane&15, row = (lane>>4)*4 + reg  [m89-verified]
    const float* Tg = sc + (size_t)(t + 1) * (N_NODE * NC);
    int n0 = nt * 128;
    float part = 0.f;
#pragma unroll
    for (int m = 0; m < 4; ++m)
#pragma unroll
        for (int j = 0; j < 4; ++j) {
            int row = wr * 64 + m * 16 + lg * 4 + j;
            const float* Trow = Tg + (size_t)(n0 + row) * 128 + wc * 64 + lr;
#pragma unroll
            for (int n = 0; n < 4; ++n) {
                float tg = Trow[n * 16];
                if (tg != 0.0f) part += fabsf(acc[m][n][j] - tg);
            }
        }
    red[tid] = part;
    __syncthreads();
    for (int s = 128; s > 0; s >>= 1) {
        if (tid < s) red[tid] += red[tid + s];
        __syncthreads();
    }
    if (tid == 0) mpart[((size_t)t * NP + p) * 8 + nt] = red[0];
}

// ---------------------------------------------------------------------------
// K2 (fp32 fallback, verified round 1) — only used if ws_size too small
__global__ __launch_bounds__(256) void k_metrics(const float* __restrict__ G,
                                                 const float* __restrict__ sc,
                                                 float* __restrict__ mpart) {
    __shared__ float As[32 * 132];
    __shared__ float Bs[32 * 132];
    __shared__ float red[256];

    int nt = blockIdx.x, p = blockIdx.y, t = blockIdx.z;
    int tid = threadIdx.x;
    int tr = tid >> 4, tc = tid & 15;
    int n0 = nt * 128;

    const float* Gp = G + (size_t)p * NN + (size_t)n0 * 1024;
    const float* Xt = sc + (size_t)t * (N_NODE * NC);

    float acc[8][8];
#pragma unroll
    for (int a = 0; a < 8; ++a)
#pragma unroll
        for (int b = 0; b < 8; ++b) acc[a][b] = 0.f;

    for (int ko = 0; ko < 1024; ko += 32) {
#pragma unroll
        for (int it = 0; it < 4; ++it) {
            int fi = tid + it * 256;
            int r = fi >> 3, q = fi & 7;
            float4 g4 = *(const float4*)(Gp + (size_t)r * 1024 + ko + q * 4);
            As[(q * 4 + 0) * 132 + r] = g4.x;
            As[(q * 4 + 1) * 132 + r] = g4.y;
            As[(q * 4 + 2) * 132 + r] = g4.z;
            As[(q * 4 + 3) * 132 + r] = g4.w;
        }
#pragma unroll
        for (int it = 0; it < 4; ++it) {
            int fi = tid + it * 256;
            int kk = fi >> 5, cq = fi & 31;
            float4 x4 = *(const float4*)(Xt + (size_t)(ko + kk) * 128 + cq * 4);
            *(float4*)(&Bs[kk * 132 + cq * 4]) = x4;
        }
        __syncthreads();
#pragma unroll
        for (int kk = 0; kk < 32; ++kk) {
            float4 a0 = *(const float4*)(&As[kk * 132 + tr * 8]);
            float4 a1 = *(const float4*)(&As[kk * 132 + tr * 8 + 4]);
            float4 b0 = *(const float4*)(&Bs[kk * 132 + tc * 8]);
            float4 b1 = *(const float4*)(&Bs[kk * 132 + tc * 8 + 4]);
            float a[8] = {a0.x, a0.y, a0.z, a0.w, a1.x, a1.y, a1.z, a1.w};
            float b[8] = {b0.x, b0.y, b0.z, b0.w, b1.x, b1.y, b1.z, b1.w};
#pragma unroll
            for (int rr = 0; rr < 8; ++rr)
#pragma unroll
                for (int cc = 0; cc < 8; ++cc)
                    acc[rr][cc] = fmaf(a[rr], b[cc], acc[rr][cc]);
        }
        __syncthreads();
    }

    const float* Tg = sc + (size_t)(t + 1) * (N_NODE * NC);
    float part = 0.f;
#pragma unroll
    for (int rr = 0; rr < 8; ++rr) {
        int n = n0 + tr * 8 + rr;
#pragma unroll
        for (int cc = 0; cc < 8; ++cc) {
            int c = tc * 8 + cc;
            float tg = Tg[(size_t)n * 128 + c];
            if (tg != 0.0f) part += fabsf(acc[rr][cc] - tg);
        }
    }
    red[tid] = part;
    __syncthreads();
    for (int s = 128; s > 0; s >>= 1) {
        if (tid < s) red[tid] += red[tid + s];
        __syncthreads();
    }
    if (tid == 0) mpart[((size_t)t * NP + p) * 8 + nt] = red[0];
}

// ---------------------------------------------------------------------------
// K2b: per-t argmin over p (first index on ties)
__global__ void k_argmin(const float* __restrict__ mpart, int* __restrict__ idx) {
    int t = blockIdx.x;
    int tid = threadIdx.x;
    __shared__ float m[NP];
    if (tid < NP) {
        float s = 0.f;
        for (int nt = 0; nt < 8; ++nt) s += mpart[((size_t)t * NP + tid) * 8 + nt];
        m[tid] = s;
    }
    __syncthreads();
    if (tid == 0) {
        int best = 0; float bv = m[0];
        for (int p = 1; p < NP; ++p)
            if (m[p] < bv) { bv = m[p]; best = p; }
        idx[t] = best;
    }
}

// ---------------------------------------------------------------------------
__global__ void k_rowmean(const float* __restrict__ sc, float* __restrict__ meanv) {
    int r = blockIdx.x, c = threadIdx.x;
    __shared__ float red[128];
    red[c] = sc[(size_t)11 * (N_NODE * NC) + (size_t)r * 128 + c];
    __syncthreads();
    for (int s = 64; s > 0; s >>= 1) {
        if (c < s) red[c] += red[c + s];
        __syncthreads();
    }
    if (c == 0) meanv[r] = red[0] * (1.0f / 128.0f);
}

__global__ __launch_bounds__(256) void k_cov(const float* __restrict__ sc,
                                             const float* __restrict__ meanv,
                                             float* __restrict__ cov) {
    __shared__ float Ai[64 * 133];
    __shared__ float Bj[64 * 133];
    int bi = blockIdx.x, bj = blockIdx.y;
    int tid = threadIdx.x;
    int i0 = bi * 64, j0 = bj * 64;
    const float* L = sc + (size_t)11 * (N_NODE * NC);
#pragma unroll
    for (int it = 0; it < 8; ++it) {
        int fi = tid + it * 256;
        int r = fi >> 5, q = fi & 31;
        float4 a4 = *(const float4*)(L + (size_t)(i0 + r) * 128 + q * 4);
        float ma = meanv[i0 + r];
        Ai[r * 133 + q * 4 + 0] = a4.x - ma;
        Ai[r * 133 + q * 4 + 1] = a4.y - ma;
        Ai[r * 133 + q * 4 + 2] = a4.z - ma;
        Ai[r * 133 + q * 4 + 3] = a4.w - ma;
        float4 b4 = *(const float4*)(L + (size_t)(j0 + r) * 128 + q * 4);
        float mb = meanv[j0 + r];
        Bj[r * 133 + q * 4 + 0] = b4.x - mb;
        Bj[r * 133 + q * 4 + 1] = b4.y - mb;
        Bj[r * 133 + q * 4 + 2] = b4.z - mb;
        Bj[r * 133 + q * 4 + 3] = b4.w - mb;
    }
    __syncthreads();
    int ti = tid >> 4, tj = tid & 15;
    float acc[4][4];
#pragma unroll
    for (int a = 0; a < 4; ++a)
#pragma unroll
        for (int b = 0; b < 4; ++b) acc[a][b] = 0.f;
    for (int k = 0; k < 128; ++k) {
        float a[4], b[4];
#pragma unroll
        for (int rr = 0; rr < 4; ++rr) a[rr] = Ai[(ti * 4 + rr) * 133 + k];
#pragma unroll
        for (int cc = 0; cc < 4; ++cc) b[cc] = Bj[(tj * 4 + cc) * 133 + k];
#pragma unroll
        for (int rr = 0; rr < 4; ++rr)
#pragma unroll
            for (int cc = 0; cc < 4; ++cc)
                acc[rr][cc] = fmaf(a[rr], b[cc], acc[rr][cc]);
    }
#pragma unroll
    for (int rr = 0; rr < 4; ++rr)
#pragma unroll
        for (int cc = 0; cc < 4; ++cc)
            cov[(size_t)(i0 + ti * 4 + rr) * 1024 + j0 + tj * 4 + cc] =
                acc[rr][cc] * (1.0f / 127.0f);
}

// ---------------------------------------------------------------------------
__global__ __launch_bounds__(256) void k_gi_part(const float* __restrict__ Wih,
                                                 const float* __restrict__ G,
                                                 const float* __restrict__ cov,
                                                 const int* __restrict__ idx,
                                                 float* __restrict__ gipart) {
    int kc = blockIdx.x;
    int jg = blockIdx.y;
    int tid = threadIdx.x;
    int lane = tid & 63, wv = tid >> 6;
    int j0 = jg * 8 + wv * 2;

    const float* ctx[12];
#pragma unroll
    for (int t = 0; t < 11; ++t) ctx[t] = G + (size_t)idx[t] * NN;
    ctx[11] = cov;

    size_t kbase = (size_t)kc * 8192 + (size_t)lane * 4;
    const float* w0 = Wih + (size_t)j0 * NN;
    const float* w1 = Wih + (size_t)(j0 + 1) * NN;

    float acc[2][12];
#pragma unroll
    for (int j = 0; j < 2; ++j)
#pragma unroll
        for (int t = 0; t < 12; ++t) acc[j][t] = 0.f;

    for (int s = 0; s < 32; ++s) {
        size_t k = kbase + (size_t)s * 256;
        float4 wa = *(const float4*)(w0 + k);
        float4 wb = *(const float4*)(w1 + k);
#pragma unroll
        for (int t = 0; t < 12; ++t) {
            float4 x = *(const float4*)(ctx[t] + k);
            acc[0][t] += wa.x * x.x + wa.y * x.y + wa.z * x.z + wa.w * x.w;
            acc[1][t] += wb.x * x.x + wb.y * x.y + wb.z * x.z + wb.w * x.w;
        }
    }
#pragma unroll
    for (int j = 0; j < 2; ++j)
#pragma unroll
        for (int t = 0; t < 12; ++t) {
            float v = acc[j][t];
            for (int off = 32; off > 0; off >>= 1) v += __shfl_xor(v, off);
            if (lane == 0)
                gipart[((size_t)(j0 + j) * T_ALL + t) * 128 + kc] = v;
        }
}

__global__ void k_gi_reduce(const float* __restrict__ gipart,
                            const float* __restrict__ bih,
                            float* __restrict__ gi) {
    int o = blockIdx.x * 256 + threadIdx.x;
    if (o >= HJ * T_ALL) return;
    int j = o / T_ALL, t = o % T_ALL;
    float s = 0.f;
    for (int kc = 0; kc < 128; ++kc) s += gipart[(size_t)o * 128 + kc];
    gi[(size_t)t * HJ + j] = s + bih[j];
}

// ---------------------------------------------------------------------------
__global__ void k_gru(const float* __restrict__ gi, const float* __restrict__ Whh,
                      const float* __restrict__ bhh, int* __restrict__ idx) {
    __shared__ float h[HH], gh[HJ];
    int tid = threadIdx.x;
    if (tid < HH) h[tid] = 0.f;
    __syncthreads();
    for (int t = 0; t < T_ALL; ++t) {
        if (tid < HJ) {
            float s = bhh[tid];
            for (int k = 0; k < HH; ++k) s += Whh[tid * HH + k] * h[k];
            gh[tid] = s;
        }
        __syncthreads();
        if (tid < HH) {
            float gr = gi[t * HJ + tid];
            float gz = gi[t * HJ + 24 + tid];
            float gn = gi[t * HJ + 48 + tid];
            float r = 1.f / (1.f + expf(-(gr + gh[tid])));
            float z = 1.f / (1.f + expf(-(gz + gh[24 + tid])));
            float ng = tanhf(gn + r * gh[48 + tid]);
            h[tid] = (1.f - z) * ng + z * h[tid];
        }
        __syncthreads();
    }
    if (tid == 0) {
        int best = 0; float bv = h[0];
        for (int k = 1; k < HH; ++k)
            if (h[k] > bv) { bv = h[k]; best = k; }
        idx[11] = best;
    }
}

// ---------------------------------------------------------------------------
__global__ void k_gather(const float* __restrict__ G, const int* __restrict__ idx,
                         float4* __restrict__ out) {
    int i = blockIdx.x * 256 + threadIdx.x;
    int t = i >> 18;
    int r = i & 262143;
    const float4* src = (const float4*)(G + (size_t)idx[t] * NN);
    out[i] = src[r];
}

// ---------------------------------------------------------------------------
extern "C" void kernel_launch(void* const* d_in, const int* in_sizes, int n_in,
                              void* d_out, int out_size, void* d_ws, size_t ws_size,
                              hipStream_t stream) {
    const float* inp = (const float*)d_in[0];
    const float* G   = (const float*)d_in[1];
    const float* Wih = (const float*)d_in[2];
    const float* Whh = (const float*)d_in[3];
    const float* bih = (const float*)d_in[4];
    const float* bhh = (const float*)d_in[5];

    float* ws = (float*)d_ws;
    float* sc     = ws + WS_SC;
    float* cov    = ws + WS_COV;
    float* mpart  = ws + WS_MPART;
    int*   idx    = (int*)(ws + WS_IDX);
    float* meanv  = ws + WS_MEAN;
    float* gipart = ws + WS_GIPART;
    float* gi     = ws + WS_GI;

    char* wsb = (char*)d_ws;
    unsigned short* Ahi = (unsigned short*)(wsb + AB_BASE_BYTES);
    unsigned short* Alo = (unsigned short*)(wsb + AB_BASE_BYTES + AHI_BYTES);
    unsigned short* Bhi = (unsigned short*)(wsb + AB_BASE_BYTES + 2 * AHI_BYTES);
    unsigned short* Blo = (unsigned short*)(wsb + AB_BASE_BYTES + 2 * AHI_BYTES + BHI_BYTES);

    bool use_mfma = (ws_size >= WS_NEED_BYTES);

    k_build_sc<<<128, 256, 0, stream>>>(inp, sc);
    if (use_mfma) {
        k_cvt_A<<<6144, 256, 0, stream>>>(G, Ahi, Alo);
        k_cvt_B<<<352, 256, 0, stream>>>(sc, Bhi, Blo);
        k_metrics_mfma<<<2112, 256, 0, stream>>>(Ahi, Alo, Bhi, Blo, sc, mpart);
    } else {
        k_metrics<<<dim3(8, NP, T1), 256, 0, stream>>>(G, sc, mpart);
    }
    k_argmin<<<T1, 32, 0, stream>>>(mpart, idx);
    k_rowmean<<<1024, 128, 0, stream>>>(sc, meanv);
    k_cov<<<dim3(16, 16), 256, 0, stream>>>(sc, meanv, cov);
    k_gi_part<<<dim3(128, 9), 256, 0, stream>>>(Wih, G, cov, idx, gipart);
    k_gi_reduce<<<4, 256, 0, stream>>>(gipart, bih, gi);
    k_gru<<<1, 128, 0, stream>>>(gi, Whh, bhh, idx);
    k_gather<<<12288, 256, 0, stream>>>(G, idx, (float4*)d_out);
}

// Round 4
// 368.385 us; speedup vs baseline: 1.2015x; 1.2015x over previous
//
#include <hip/hip_runtime.h>
#include <math.h>
#include <stdint.h>

#define N_NODE 1024
#define NC 128            // b*d = 64*2
#define T_ALL 12
#define T1 11
#define NP 24             // period / number of graphs
#define NN (N_NODE*N_NODE)   // 1048576
#define HJ 72             // 3*H
#define HH 24             // H

// ---- workspace layout (float offsets for legacy part) ----
#define WS_SC     0                                   // 12*1024*128 = 1572864
#define WS_COV    (WS_SC + T_ALL*N_NODE*NC)           // + 1048576
#define WS_MPART  (WS_COV + NN)                       // + 11*24*8 = 2112
#define WS_IDX    (WS_MPART + T1*NP*8)                // + 16 (ints)
#define WS_MEAN   (WS_IDX + 16)                       // + 1024
#define WS_GIPART (WS_MEAN + N_NODE)                  // + 128*72*12 = 110592
#define WS_GI     (WS_GIPART + 128*HJ*T_ALL)          // + 864
#define WS_BASE_FLOATS (WS_GI + HJ*T_ALL)             // = 2736064

// byte offsets for fp16 tile arrays
#define AB_BASE_BYTES ((size_t)WS_BASE_FLOATS * 4)    // 10944256, 16B aligned
#define AHI_BYTES ((size_t)24*1024*1024*2)            // 50331648 (A fp16, single)
#define BHI_BYTES ((size_t)11*32*4096*2)              // 2883584 (per B image)
#define WS_NEED_BYTES (AB_BASE_BYTES + AHI_BYTES + 2*BHI_BYTES)  // ~67MB

typedef __attribute__((ext_vector_type(8))) unsigned short ushort8v;
typedef __attribute__((ext_vector_type(8))) _Float16 half8v;
typedef __attribute__((ext_vector_type(4))) float f32x4;

// ---------------------------------------------------------------------------
__device__ __forceinline__ void gload16(const void* g, void* l) {
    __builtin_amdgcn_global_load_lds(
        (const __attribute__((address_space(1))) uint32_t*)g,
        (__attribute__((address_space(3))) uint32_t*)l, 16, 0, 0);
}

__device__ __forceinline__ unsigned short f16_bits(_Float16 h) {
    union { _Float16 f; unsigned short u; } cv; cv.f = h; return cv.u;
}

// ---------------------------------------------------------------------------
// K1: sc[t][n][c] = inputs[b][n][t*2+dd], c = 2b+dd. LDS-tiled transpose.
__global__ __launch_bounds__(256) void k_build_sc(const float* __restrict__ inp,
                                                  float* __restrict__ sc) {
    __shared__ float ld[12830];   // addr(n,b,td) = n*401 + b*25 + td
    int b0 = (blockIdx.x & 3) * 16;
    int n0 = (blockIdx.x >> 2) * 32;
    for (int idx = threadIdx.x; idx < 3072; idx += 256) {
        int bb = idx / 192;
        int rem = idx - bb * 192;
        int nn = rem / 6;
        int q  = rem - nn * 6;
        const float4 v = *(const float4*)(inp +
            ((size_t)(b0 + bb) * 1024 + (n0 + nn)) * 24 + q * 4);
        int base = nn * 401 + bb * 25 + q * 4;
        ld[base + 0] = v.x; ld[base + 1] = v.y;
        ld[base + 2] = v.z; ld[base + 3] = v.w;
    }
    __syncthreads();
    for (int idx = threadIdx.x; idx < 12288; idx += 256) {
        int t = idx >> 10;
        int rem = idx & 1023;
        int nn = rem >> 5, cc = rem & 31;
        int bb = cc >> 1, dd = cc & 1;
        sc[(size_t)t * 131072 + (size_t)(n0 + nn) * 128 + b0 * 2 + cc] =
            ld[nn * 401 + bb * 25 + t * 2 + dd];
    }
}

// ---------------------------------------------------------------------------
// Convert graphs -> tile-contiguous, XOR-swizzled fp16 (single image).
// Tile (p,nt,ks) = G[p][nt*128..+128][ks*32..+32], 4096 ushort:
//   byte_off(r,kk) = (r*64 + kk*2) ^ ((r&7)<<4)
__global__ __launch_bounds__(256) void k_cvt_A(const float* __restrict__ G,
                                               unsigned short* __restrict__ Ahi) {
    int tile = blockIdx.x;            // 0..6143 = (p*8+nt)*32+ks
    int ks = tile & 31;
    int pn = tile >> 5;
    int nt = pn & 7, p = pn >> 3;
    const float* Gt = G + (size_t)p * NN + (size_t)(nt * 128) * 1024 + ks * 32;
    size_t base = (size_t)tile * 4096;
#pragma unroll
    for (int g2 = 0; g2 < 2; ++g2) {
        int gid = threadIdx.x * 2 + g2;   // 0..511
        int r = gid >> 2, gg = gid & 3;
        const float* src = Gt + (size_t)r * 1024 + gg * 8;
        ushort8v h;
#pragma unroll
        for (int j = 0; j < 8; ++j)
            h[j] = f16_bits((_Float16)src[j]);
        int offu = ((r * 64 + gg * 16) ^ ((r & 7) << 4)) >> 1;  // ushort index
        *(ushort8v*)(Ahi + base + offu) = h;
    }
}

// Convert sc[t] (t<11) -> transposed [c][kk] swizzled fp16 hi/lo pair.
// Tile (t,ks): element (c,kk) = sc[t][ks*32+kk][c]; byte_off = (c*64+kk*2)^((c&7)<<4)
__global__ __launch_bounds__(256) void k_cvt_B(const float* __restrict__ sc,
                                               unsigned short* __restrict__ Bhi,
                                               unsigned short* __restrict__ Blo) {
    __shared__ float s[32][129];
    int tile = blockIdx.x;            // 0..351 = t*32+ks
    int ks = tile & 31;
    int t = tile >> 5;
    const float* S = sc + (size_t)t * (N_NODE * NC) + (size_t)ks * 32 * 128;
#pragma unroll
    for (int i = 0; i < 4; ++i) {
        int fi = threadIdx.x + i * 256;      // float4 index 0..1023
        int m = fi >> 5, c4 = fi & 31;
        float4 v = *(const float4*)(S + (size_t)m * 128 + c4 * 4);
        s[m][c4 * 4 + 0] = v.x;
        s[m][c4 * 4 + 1] = v.y;
        s[m][c4 * 4 + 2] = v.z;
        s[m][c4 * 4 + 3] = v.w;
    }
    __syncthreads();
    size_t base = (size_t)tile * 4096;
#pragma unroll
    for (int g2 = 0; g2 < 2; ++g2) {
        int gid = threadIdx.x * 2 + g2;   // 0..511
        int c = gid >> 2, gg = gid & 3;
        ushort8v h, l;
#pragma unroll
        for (int j = 0; j < 8; ++j) {
            float f = s[gg * 8 + j][c];
            _Float16 hh = (_Float16)f;
            _Float16 ll = (_Float16)(f - (float)hh);
            h[j] = f16_bits(hh); l[j] = f16_bits(ll);
        }
        int offu = ((c * 64 + gg * 16) ^ ((c & 7) << 4)) >> 1;
        *(ushort8v*)(Bhi + base + offu) = h;
        *(ushort8v*)(Blo + base + offu) = l;
    }
}

// ---------------------------------------------------------------------------
// K2 (MFMA): fp16 2-product GEMM + masked abs-diff reduce.
//   pred = ah*(bh+bl)  (error = al*b ~ 2^-12 rel, metric-safe by ~1000x)
// R2-proven schedule: stage -> barrier -> compute -> barrier, single buffer.
// 3 images x 8KB = 24KB LDS -> 4+ blocks/CU; launch_bounds(256,4) caps VGPR.
__global__ __launch_bounds__(256, 4) void k_metrics_mfma(
        const unsigned short* __restrict__ Ahi,
        const unsigned short* __restrict__ Bhi, const unsigned short* __restrict__ Blo,
        const float* __restrict__ sc, float* __restrict__ mpart) {
    __shared__ unsigned short lds[3][4096];   // A, B_hi, B_lo (8KB each)
    __shared__ float red[256];

    int bid = blockIdx.x;                      // 0..2111
    int orig = (bid & 7) * 264 + (bid >> 3);   // chunked XCD swizzle (2112 = 8*264)
    int t = orig % 11;
    int pn = orig / 11;                        // 0..191
    int nt = pn & 7, p = pn >> 3;

    int tid = threadIdx.x;
    int lane = tid & 63, wv = tid >> 6;
    int wr = wv >> 1, wc = wv & 1;
    int lr = lane & 15, lg = lane >> 4;

    const unsigned short* srcA  = Ahi + (size_t)(p * 8 + nt) * 32 * 4096;
    const unsigned short* srcBh = Bhi + (size_t)t * 32 * 4096;
    const unsigned short* srcBl = Blo + (size_t)t * 32 * 4096;

    f32x4 acc[4][4];
#pragma unroll
    for (int m = 0; m < 4; ++m)
#pragma unroll
        for (int n = 0; n < 4; ++n)
            acc[m][n] = (f32x4){0.f, 0.f, 0.f, 0.f};

    int aoff[4], boff[4];
#pragma unroll
    for (int m = 0; m < 4; ++m) {
        int row = wr * 64 + m * 16 + lr;
        aoff[m] = (row * 64 + lg * 16) ^ ((row & 7) << 4);
    }
#pragma unroll
    for (int n = 0; n < 4; ++n) {
        int col = wc * 64 + n * 16 + lr;
        boff[n] = (col * 64 + lg * 16) ^ ((col & 7) << 4);
    }

    const char* L0 = (const char*)&lds[0][0];
    const char* L1 = (const char*)&lds[1][0];
    const char* L2 = (const char*)&lds[2][0];

    for (int ks = 0; ks < 32; ++ks) {
        // stage 3 images (24 x 1KB chunks) across 4 waves: wave wv takes c = wv+4i
        const unsigned short* s0 = srcA  + (size_t)ks * 4096;
        const unsigned short* s1 = srcBh + (size_t)ks * 4096;
        const unsigned short* s2 = srcBl + (size_t)ks * 4096;
#pragma unroll
        for (int i = 0; i < 6; ++i) {
            int c = wv + i * 4;              // 0..23
            int img = c >> 3, seg = c & 7;
            const unsigned short* sp = (img == 0 ? s0 : img == 1 ? s1 : s2)
                                       + seg * 512 + lane * 8;
            gload16(sp, &lds[img][seg * 512]);
        }
        __syncthreads();

        // bh/bl resident (32 VGPR), ah streamed per m -> ~100 VGPR total
        half8v bh[4], bl[4];
#pragma unroll
        for (int n = 0; n < 4; ++n) {
            bh[n] = *(const half8v*)(L1 + boff[n]);
            bl[n] = *(const half8v*)(L2 + boff[n]);
        }
#pragma unroll
        for (int m = 0; m < 4; ++m) {
            half8v ah = *(const half8v*)(L0 + aoff[m]);
#pragma unroll
            for (int n = 0; n < 4; ++n) {
                acc[m][n] = __builtin_amdgcn_mfma_f32_16x16x32_f16(ah, bh[n], acc[m][n], 0, 0, 0);
                acc[m][n] = __builtin_amdgcn_mfma_f32_16x16x32_f16(ah, bl[n], acc[m][n], 0, 0, 0);
            }
        }
        __syncthreads();
    }

    // epilogue: masked |pred - target| partial sum
    // C/D layout: col = lane&15, row = (lane>>4)*4 + reg  (dtype-independent)
    const float* Tg = sc + (size_t)(t + 1) * (N_NODE * NC);
    int n0 = nt * 128;
    float part = 0.f;
#pragma unroll
    for (int m = 0; m < 4; ++m)
#pragma unroll
        for (int j = 0; j < 4; ++j) {
            int row = wr * 64 + m * 16 + lg * 4 + j;
            const float* Trow = Tg + (size_t)(n0 + row) * 128 + wc * 64 + lr;
#pragma unroll
            for (int n = 0; n < 4; ++n) {
                float tg = Trow[n * 16];
                if (tg != 0.0f) part += fabsf(acc[m][n][j] - tg);
            }
        }
    red[tid] = part;
    __syncthreads();
    for (int s = 128; s > 0; s >>= 1) {
        if (tid < s) red[tid] += red[tid + s];
        __syncthreads();
    }
    if (tid == 0) mpart[((size_t)t * NP + p) * 8 + nt] = red[0];
}

// ---------------------------------------------------------------------------
// K2 (fp32 fallback, verified round 1) — only used if ws_size too small
__global__ __launch_bounds__(256) void k_metrics(const float* __restrict__ G,
                                                 const float* __restrict__ sc,
                                                 float* __restrict__ mpart) {
    __shared__ float As[32 * 132];
    __shared__ float Bs[32 * 132];
    __shared__ float red[256];

    int nt = blockIdx.x, p = blockIdx.y, t = blockIdx.z;
    int tid = threadIdx.x;
    int tr = tid >> 4, tc = tid & 15;
    int n0 = nt * 128;

    const float* Gp = G + (size_t)p * NN + (size_t)n0 * 1024;
    const float* Xt = sc + (size_t)t * (N_NODE * NC);

    float acc[8][8];
#pragma unroll
    for (int a = 0; a < 8; ++a)
#pragma unroll
        for (int b = 0; b < 8; ++b) acc[a][b] = 0.f;

    for (int ko = 0; ko < 1024; ko += 32) {
#pragma unroll
        for (int it = 0; it < 4; ++it) {
            int fi = tid + it * 256;
            int r = fi >> 3, q = fi & 7;
            float4 g4 = *(const float4*)(Gp + (size_t)r * 1024 + ko + q * 4);
            As[(q * 4 + 0) * 132 + r] = g4.x;
            As[(q * 4 + 1) * 132 + r] = g4.y;
            As[(q * 4 + 2) * 132 + r] = g4.z;
            As[(q * 4 + 3) * 132 + r] = g4.w;
        }
#pragma unroll
        for (int it = 0; it < 4; ++it) {
            int fi = tid + it * 256;
            int kk = fi >> 5, cq = fi & 31;
            float4 x4 = *(const float4*)(Xt + (size_t)(ko + kk) * 128 + cq * 4);
            *(float4*)(&Bs[kk * 132 + cq * 4]) = x4;
        }
        __syncthreads();
#pragma unroll
        for (int kk = 0; kk < 32; ++kk) {
            float4 a0 = *(const float4*)(&As[kk * 132 + tr * 8]);
            float4 a1 = *(const float4*)(&As[kk * 132 + tr * 8 + 4]);
            float4 b0 = *(const float4*)(&Bs[kk * 132 + tc * 8]);
            float4 b1 = *(const float4*)(&Bs[kk * 132 + tc * 8 + 4]);
            float a[8] = {a0.x, a0.y, a0.z, a0.w, a1.x, a1.y, a1.z, a1.w};
            float b[8] = {b0.x, b0.y, b0.z, b0.w, b1.x, b1.y, b1.z, b1.w};
#pragma unroll
            for (int rr = 0; rr < 8; ++rr)
#pragma unroll
                for (int cc = 0; cc < 8; ++cc)
                    acc[rr][cc] = fmaf(a[rr], b[cc], acc[rr][cc]);
        }
        __syncthreads();
    }

    const float* Tg = sc + (size_t)(t + 1) * (N_NODE * NC);
    float part = 0.f;
#pragma unroll
    for (int rr = 0; rr < 8; ++rr) {
        int n = n0 + tr * 8 + rr;
#pragma unroll
        for (int cc = 0; cc < 8; ++cc) {
            int c = tc * 8 + cc;
            float tg = Tg[(size_t)n * 128 + c];
            if (tg != 0.0f) part += fabsf(acc[rr][cc] - tg);
        }
    }
    red[tid] = part;
    __syncthreads();
    for (int s = 128; s > 0; s >>= 1) {
        if (tid < s) red[tid] += red[tid + s];
        __syncthreads();
    }
    if (tid == 0) mpart[((size_t)t * NP + p) * 8 + nt] = red[0];
}

// ---------------------------------------------------------------------------
// K2b: per-t argmin over p (first index on ties)
__global__ void k_argmin(const float* __restrict__ mpart, int* __restrict__ idx) {
    int t = blockIdx.x;
    int tid = threadIdx.x;
    __shared__ float m[NP];
    if (tid < NP) {
        float s = 0.f;
        for (int nt = 0; nt < 8; ++nt) s += mpart[((size_t)t * NP + tid) * 8 + nt];
        m[tid] = s;
    }
    __syncthreads();
    if (tid == 0) {
        int best = 0; float bv = m[0];
        for (int p = 1; p < NP; ++p)
            if (m[p] < bv) { bv = m[p]; best = p; }
        idx[t] = best;
    }
}

// ---------------------------------------------------------------------------
__global__ void k_rowmean(const float* __restrict__ sc, float* __restrict__ meanv) {
    int r = blockIdx.x, c = threadIdx.x;
    __shared__ float red[128];
    red[c] = sc[(size_t)11 * (N_NODE * NC) + (size_t)r * 128 + c];
    __syncthreads();
    for (int s = 64; s > 0; s >>= 1) {
        if (c < s) red[c] += red[c + s];
        __syncthreads();
    }
    if (c == 0) meanv[r] = red[0] * (1.0f / 128.0f);
}

__global__ __launch_bounds__(256) void k_cov(const float* __restrict__ sc,
                                             const float* __restrict__ meanv,
                                             float* __restrict__ cov) {
    __shared__ float Ai[64 * 133];
    __shared__ float Bj[64 * 133];
    int bi = blockIdx.x, bj = blockIdx.y;
    int tid = threadIdx.x;
    int i0 = bi * 64, j0 = bj * 64;
    const float* L = sc + (size_t)11 * (N_NODE * NC);
#pragma unroll
    for (int it = 0; it < 8; ++it) {
        int fi = tid + it * 256;
        int r = fi >> 5, q = fi & 31;
        float4 a4 = *(const float4*)(L + (size_t)(i0 + r) * 128 + q * 4);
        float ma = meanv[i0 + r];
        Ai[r * 133 + q * 4 + 0] = a4.x - ma;
        Ai[r * 133 + q * 4 + 1] = a4.y - ma;
        Ai[r * 133 + q * 4 + 2] = a4.z - ma;
        Ai[r * 133 + q * 4 + 3] = a4.w - ma;
        float4 b4 = *(const float4*)(L + (size_t)(j0 + r) * 128 + q * 4);
        float mb = meanv[j0 + r];
        Bj[r * 133 + q * 4 + 0] = b4.x - mb;
        Bj[r * 133 + q * 4 + 1] = b4.y - mb;
        Bj[r * 133 + q * 4 + 2] = b4.z - mb;
        Bj[r * 133 + q * 4 + 3] = b4.w - mb;
    }
    __syncthreads();
    int ti = tid >> 4, tj = tid & 15;
    float acc[4][4];
#pragma unroll
    for (int a = 0; a < 4; ++a)
#pragma unroll
        for (int b = 0; b < 4; ++b) acc[a][b] = 0.f;
    for (int k = 0; k < 128; ++k) {
        float a[4], b[4];
#pragma unroll
        for (int rr = 0; rr < 4; ++rr) a[rr] = Ai[(ti * 4 + rr) * 133 + k];
#pragma unroll
        for (int cc = 0; cc < 4; ++cc) b[cc] = Bj[(tj * 4 + cc) * 133 + k];
#pragma unroll
        for (int rr = 0; rr < 4; ++rr)
#pragma unroll
            for (int cc = 0; cc < 4; ++cc)
                acc[rr][cc] = fmaf(a[rr], b[cc], acc[rr][cc]);
    }
#pragma unroll
    for (int rr = 0; rr < 4; ++rr)
#pragma unroll
        for (int cc = 0; cc < 4; ++cc)
            cov[(size_t)(i0 + ti * 4 + rr) * 1024 + j0 + tj * 4 + cc] =
                acc[rr][cc] * (1.0f / 127.0f);
}

// ---------------------------------------------------------------------------
__global__ __launch_bounds__(256) void k_gi_part(const float* __restrict__ Wih,
                                                 const float* __restrict__ G,
                                                 const float* __restrict__ cov,
                                                 const int* __restrict__ idx,
                                                 float* __restrict__ gipart) {
    int kc = blockIdx.x;
    int jg = blockIdx.y;
    int tid = threadIdx.x;
    int lane = tid & 63, wv = tid >> 6;
    int j0 = jg * 8 + wv * 2;

    const float* ctx[12];
#pragma unroll
    for (int t = 0; t < 11; ++t) ctx[t] = G + (size_t)idx[t] * NN;
    ctx[11] = cov;

    size_t kbase = (size_t)kc * 8192 + (size_t)lane * 4;
    const float* w0 = Wih + (size_t)j0 * NN;
    const float* w1 = Wih + (size_t)(j0 + 1) * NN;

    float acc[2][12];
#pragma unroll
    for (int j = 0; j < 2; ++j)
#pragma unroll
        for (int t = 0; t < 12; ++t) acc[j][t] = 0.f;

    for (int s = 0; s < 32; ++s) {
        size_t k = kbase + (size_t)s * 256;
        float4 wa = *(const float4*)(w0 + k);
        float4 wb = *(const float4*)(w1 + k);
#pragma unroll
        for (int t = 0; t < 12; ++t) {
            float4 x = *(const float4*)(ctx[t] + k);
            acc[0][t] += wa.x * x.x + wa.y * x.y + wa.z * x.z + wa.w * x.w;
            acc[1][t] += wb.x * x.x + wb.y * x.y + wb.z * x.z + wb.w * x.w;
        }
    }
#pragma unroll
    for (int j = 0; j < 2; ++j)
#pragma unroll
        for (int t = 0; t < 12; ++t) {
            float v = acc[j][t];
            for (int off = 32; off > 0; off >>= 1) v += __shfl_xor(v, off);
            if (lane == 0)
                gipart[((size_t)(j0 + j) * T_ALL + t) * 128 + kc] = v;
        }
}

__global__ void k_gi_reduce(const float* __restrict__ gipart,
                            const float* __restrict__ bih,
                            float* __restrict__ gi) {
    int o = blockIdx.x * 256 + threadIdx.x;
    if (o >= HJ * T_ALL) return;
    int j = o / T_ALL, t = o % T_ALL;
    float s = 0.f;
    for (int kc = 0; kc < 128; ++kc) s += gipart[(size_t)o * 128 + kc];
    gi[(size_t)t * HJ + j] = s + bih[j];
}

// ---------------------------------------------------------------------------
__global__ void k_gru(const float* __restrict__ gi, const float* __restrict__ Whh,
                      const float* __restrict__ bhh, int* __restrict__ idx) {
    __shared__ float h[HH], gh[HJ];
    int tid = threadIdx.x;
    if (tid < HH) h[tid] = 0.f;
    __syncthreads();
    for (int t = 0; t < T_ALL; ++t) {
        if (tid < HJ) {
            float s = bhh[tid];
            for (int k = 0; k < HH; ++k) s += Whh[tid * HH + k] * h[k];
            gh[tid] = s;
        }
        __syncthreads();
        if (tid < HH) {
            float gr = gi[t * HJ + tid];
            float gz = gi[t * HJ + 24 + tid];
            float gn = gi[t * HJ + 48 + tid];
            float r = 1.f / (1.f + expf(-(gr + gh[tid])));
            float z = 1.f / (1.f + expf(-(gz + gh[24 + tid])));
            float ng = tanhf(gn + r * gh[48 + tid]);
            h[tid] = (1.f - z) * ng + z * h[tid];
        }
        __syncthreads();
    }
    if (tid == 0) {
        int best = 0; float bv = h[0];
        for (int k = 1; k < HH; ++k)
            if (h[k] > bv) { bv = h[k]; best = k; }
        idx[11] = best;
    }
}

// ---------------------------------------------------------------------------
__global__ void k_gather(const float* __restrict__ G, const int* __restrict__ idx,
                         float4* __restrict__ out) {
    int i = blockIdx.x * 256 + threadIdx.x;
    int t = i >> 18;
    int r = i & 262143;
    const float4* src = (const float4*)(G + (size_t)idx[t] * NN);
    out[i] = src[r];
}

// ---------------------------------------------------------------------------
extern "C" void kernel_launch(void* const* d_in, const int* in_sizes, int n_in,
                              void* d_out, int out_size, void* d_ws, size_t ws_size,
                              hipStream_t stream) {
    const float* inp = (const float*)d_in[0];
    const float* G   = (const float*)d_in[1];
    const float* Wih = (const float*)d_in[2];
    const float* Whh = (const float*)d_in[3];
    const float* bih = (const float*)d_in[4];
    const float* bhh = (const float*)d_in[5];

    float* ws = (float*)d_ws;
    float* sc     = ws + WS_SC;
    float* cov    = ws + WS_COV;
    float* mpart  = ws + WS_MPART;
    int*   idx    = (int*)(ws + WS_IDX);
    float* meanv  = ws + WS_MEAN;
    float* gipart = ws + WS_GIPART;
    float* gi     = ws + WS_GI;

    char* wsb = (char*)d_ws;
    unsigned short* Ahi = (unsigned short*)(wsb + AB_BASE_BYTES);
    unsigned short* Bhi = (unsigned short*)(wsb + AB_BASE_BYTES + AHI_BYTES);
    unsigned short* Blo = (unsigned short*)(wsb + AB_BASE_BYTES + AHI_BYTES + BHI_BYTES);

    bool use_mfma = (ws_size >= WS_NEED_BYTES);

    k_build_sc<<<128, 256, 0, stream>>>(inp, sc);
    if (use_mfma) {
        k_cvt_A<<<6144, 256, 0, stream>>>(G, Ahi);
        k_cvt_B<<<352, 256, 0, stream>>>(sc, Bhi, Blo);
        k_metrics_mfma<<<2112, 256, 0, stream>>>(Ahi, Bhi, Blo, sc, mpart);
    } else {
        k_metrics<<<dim3(8, NP, T1), 256, 0, stream>>>(G, sc, mpart);
    }
    k_argmin<<<T1, 32, 0, stream>>>(mpart, idx);
    k_rowmean<<<1024, 128, 0, stream>>>(sc, meanv);
    k_cov<<<dim3(16, 16), 256, 0, stream>>>(sc, meanv, cov);
    k_gi_part<<<dim3(128, 9), 256, 0, stream>>>(Wih, G, cov, idx, gipart);
    k_gi_reduce<<<4, 256, 0, stream>>>(gipart, bih, gi);
    k_gru<<<1, 128, 0, stream>>>(gi, Whh, bhh, idx);
    k_gather<<<12288, 256, 0, stream>>>(G, idx, (float4*)d_out);
}

// Round 5
// 293.382 us; speedup vs baseline: 1.5087x; 1.2556x over previous
//
#include <hip/hip_runtime.h>
#include <math.h>
#include <stdint.h>

#define N_NODE 1024
#define NC 128            // b*d = 64*2
#define T_ALL 12
#define T1 11
#define NP 24             // period / number of graphs
#define NN (N_NODE*N_NODE)   // 1048576
#define HJ 72             // 3*H
#define HH 24             // H

// ---- workspace layout (float offsets for legacy part) ----
#define WS_SC     0                                   // 12*1024*128 = 1572864
#define WS_COV    (WS_SC + T_ALL*N_NODE*NC)           // + 1048576
#define WS_MPART  (WS_COV + NN)                       // + 11*24*8 = 2112
#define WS_IDX    (WS_MPART + T1*NP*8)                // + 16 (ints)
#define WS_MEAN   (WS_IDX + 16)                       // + 1024
#define WS_GIPART (WS_MEAN + N_NODE)                  // + 128*72*12 = 110592
#define WS_GI     (WS_GIPART + 128*HJ*T_ALL)          // + 864
#define WS_BASE_FLOATS (WS_GI + HJ*T_ALL)             // = 2736064

// byte offsets for fp16 tile arrays
#define AB_BASE_BYTES ((size_t)WS_BASE_FLOATS * 4)    // 10944256, 16B aligned
#define AHI_BYTES ((size_t)24*1024*1024*2)            // 50331648 (A fp16)
#define BHI_BYTES ((size_t)11*32*4096*2)              // 2883584 (B fp16)
#define WS_NEED_BYTES (AB_BASE_BYTES + AHI_BYTES + BHI_BYTES)  // ~64MB

typedef __attribute__((ext_vector_type(8))) unsigned short ushort8v;
typedef __attribute__((ext_vector_type(8))) _Float16 half8v;
typedef __attribute__((ext_vector_type(4))) float f32x4;

// ---------------------------------------------------------------------------
__device__ __forceinline__ void gload16(const void* g, void* l) {
    __builtin_amdgcn_global_load_lds(
        (const __attribute__((address_space(1))) uint32_t*)g,
        (__attribute__((address_space(3))) uint32_t*)l, 16, 0, 0);
}

__device__ __forceinline__ unsigned short f16_bits(_Float16 h) {
    union { _Float16 f; unsigned short u; } cv; cv.f = h; return cv.u;
}

// ---------------------------------------------------------------------------
// K1: sc[t][n][c] = inputs[b][n][t*2+dd], c = 2b+dd. LDS-tiled transpose.
__global__ __launch_bounds__(256) void k_build_sc(const float* __restrict__ inp,
                                                  float* __restrict__ sc) {
    __shared__ float ld[12830];   // addr(n,b,td) = n*401 + b*25 + td
    int b0 = (blockIdx.x & 3) * 16;
    int n0 = (blockIdx.x >> 2) * 32;
    for (int idx = threadIdx.x; idx < 3072; idx += 256) {
        int bb = idx / 192;
        int rem = idx - bb * 192;
        int nn = rem / 6;
        int q  = rem - nn * 6;
        const float4 v = *(const float4*)(inp +
            ((size_t)(b0 + bb) * 1024 + (n0 + nn)) * 24 + q * 4);
        int base = nn * 401 + bb * 25 + q * 4;
        ld[base + 0] = v.x; ld[base + 1] = v.y;
        ld[base + 2] = v.z; ld[base + 3] = v.w;
    }
    __syncthreads();
    for (int idx = threadIdx.x; idx < 12288; idx += 256) {
        int t = idx >> 10;
        int rem = idx & 1023;
        int nn = rem >> 5, cc = rem & 31;
        int bb = cc >> 1, dd = cc & 1;
        sc[(size_t)t * 131072 + (size_t)(n0 + nn) * 128 + b0 * 2 + cc] =
            ld[nn * 401 + bb * 25 + t * 2 + dd];
    }
}

// ---------------------------------------------------------------------------
// Convert graphs -> tile-contiguous, XOR-swizzled fp16 (single image).
// Tile (p,nt,ks) = G[p][nt*128..+128][ks*32..+32], 4096 ushort:
//   byte_off(r,kk) = (r*64 + kk*2) ^ ((r&7)<<4)
__global__ __launch_bounds__(256) void k_cvt_A(const float* __restrict__ G,
                                               unsigned short* __restrict__ Ahi) {
    int tile = blockIdx.x;            // 0..6143 = (p*8+nt)*32+ks
    int ks = tile & 31;
    int pn = tile >> 5;
    int nt = pn & 7, p = pn >> 3;
    const float* Gt = G + (size_t)p * NN + (size_t)(nt * 128) * 1024 + ks * 32;
    size_t base = (size_t)tile * 4096;
#pragma unroll
    for (int g2 = 0; g2 < 2; ++g2) {
        int gid = threadIdx.x * 2 + g2;   // 0..511
        int r = gid >> 2, gg = gid & 3;
        const float* src = Gt + (size_t)r * 1024 + gg * 8;
        ushort8v h;
#pragma unroll
        for (int j = 0; j < 8; ++j)
            h[j] = f16_bits((_Float16)src[j]);
        int offu = ((r * 64 + gg * 16) ^ ((r & 7) << 4)) >> 1;  // ushort index
        *(ushort8v*)(Ahi + base + offu) = h;
    }
}

// Convert sc[t] (t<11) -> transposed [c][kk] swizzled fp16.
// Tile (t,ks): element (c,kk) = sc[t][ks*32+kk][c]; byte_off = (c*64+kk*2)^((c&7)<<4)
__global__ __launch_bounds__(256) void k_cvt_B(const float* __restrict__ sc,
                                               unsigned short* __restrict__ Bhi) {
    __shared__ float s[32][129];
    int tile = blockIdx.x;            // 0..351 = t*32+ks
    int ks = tile & 31;
    int t = tile >> 5;
    const float* S = sc + (size_t)t * (N_NODE * NC) + (size_t)ks * 32 * 128;
#pragma unroll
    for (int i = 0; i < 4; ++i) {
        int fi = threadIdx.x + i * 256;      // float4 index 0..1023
        int m = fi >> 5, c4 = fi & 31;
        float4 v = *(const float4*)(S + (size_t)m * 128 + c4 * 4);
        s[m][c4 * 4 + 0] = v.x;
        s[m][c4 * 4 + 1] = v.y;
        s[m][c4 * 4 + 2] = v.z;
        s[m][c4 * 4 + 3] = v.w;
    }
    __syncthreads();
    size_t base = (size_t)tile * 4096;
#pragma unroll
    for (int g2 = 0; g2 < 2; ++g2) {
        int gid = threadIdx.x * 2 + g2;   // 0..511
        int c = gid >> 2, gg = gid & 3;
        ushort8v h;
#pragma unroll
        for (int j = 0; j < 8; ++j)
            h[j] = f16_bits((_Float16)s[gg * 8 + j][c]);
        int offu = ((c * 64 + gg * 16) ^ ((c & 7) << 4)) >> 1;
        *(ushort8v*)(Bhi + base + offu) = h;
    }
}

// ---------------------------------------------------------------------------
// K2 (MFMA): fp16 single-product GEMM + masked abs-diff reduce.
//   pred = ah*bh  (error ~ 2^-11.3 rel; R4 passed at 2^-12-class error)
// BK=64 per barrier pair: stage 32KB (A:16K, B:16K), 32 MFMA + 16 ds_read
// per wave per step, 16 steps. LDS 33KB -> 4 blocks/CU.
__global__ __launch_bounds__(256, 4) void k_metrics_mfma(
        const unsigned short* __restrict__ Ahi,
        const unsigned short* __restrict__ Bhi,
        const float* __restrict__ sc, float* __restrict__ mpart) {
    __shared__ unsigned short lds[2][2][4096];   // [img A/B][k-half][8KB tile]
    __shared__ float red[256];

    int bid = blockIdx.x;                      // 0..2111
    int orig = (bid & 7) * 264 + (bid >> 3);   // chunked XCD swizzle (2112 = 8*264)
    int t = orig % 11;
    int pn = orig / 11;                        // 0..191
    int nt = pn & 7, p = pn >> 3;

    int tid = threadIdx.x;
    int lane = tid & 63, wv = tid >> 6;
    int wr = wv >> 1, wc = wv & 1;
    int lr = lane & 15, lg = lane >> 4;

    const unsigned short* srcA = Ahi + (size_t)(p * 8 + nt) * 32 * 4096;
    const unsigned short* srcB = Bhi + (size_t)t * 32 * 4096;

    f32x4 acc[4][4];
#pragma unroll
    for (int m = 0; m < 4; ++m)
#pragma unroll
        for (int n = 0; n < 4; ++n)
            acc[m][n] = (f32x4){0.f, 0.f, 0.f, 0.f};

    int aoff[4], boff[4];
#pragma unroll
    for (int m = 0; m < 4; ++m) {
        int row = wr * 64 + m * 16 + lr;
        aoff[m] = (row * 64 + lg * 16) ^ ((row & 7) << 4);
    }
#pragma unroll
    for (int n = 0; n < 4; ++n) {
        int col = wc * 64 + n * 16 + lr;
        boff[n] = (col * 64 + lg * 16) ^ ((col & 7) << 4);
    }

    const char* LA = (const char*)&lds[0][0][0];
    const char* LB = (const char*)&lds[1][0][0];

    for (int ks2 = 0; ks2 < 16; ++ks2) {
        // stage 32KB: A double-tile (16KB) + B double-tile (16KB) = 32 segs
        // of 1KB; wave wv takes segs wv+4i (i=0..7)
        const unsigned short* sA = srcA + (size_t)ks2 * 8192;
        const unsigned short* sB = srcB + (size_t)ks2 * 8192;
#pragma unroll
        for (int i = 0; i < 8; ++i) {
            int c = wv + i * 4;               // 0..31
            int img = c >> 4, seg = c & 15;   // seg 0..15 within 16KB image
            const unsigned short* sp = (img == 0 ? sA : sB) + seg * 512 + lane * 8;
            gload16(sp, &lds[img][seg >> 3][(seg & 7) * 512]);
        }
        __syncthreads();

        half8v bh[4][2];
#pragma unroll
        for (int n = 0; n < 4; ++n) {
            bh[n][0] = *(const half8v*)(LB + boff[n]);
            bh[n][1] = *(const half8v*)(LB + 8192 + boff[n]);
        }
#pragma unroll
        for (int m = 0; m < 4; ++m) {
            half8v ah0 = *(const half8v*)(LA + aoff[m]);
            half8v ah1 = *(const half8v*)(LA + 8192 + aoff[m]);
#pragma unroll
            for (int n = 0; n < 4; ++n) {
                acc[m][n] = __builtin_amdgcn_mfma_f32_16x16x32_f16(ah0, bh[n][0], acc[m][n], 0, 0, 0);
                acc[m][n] = __builtin_amdgcn_mfma_f32_16x16x32_f16(ah1, bh[n][1], acc[m][n], 0, 0, 0);
            }
        }
        __syncthreads();
    }

    // epilogue: masked |pred - target| partial sum
    // C/D layout: col = lane&15, row = (lane>>4)*4 + reg  (dtype-independent)
    const float* Tg = sc + (size_t)(t + 1) * (N_NODE * NC);
    int n0 = nt * 128;
    float part = 0.f;
#pragma unroll
    for (int m = 0; m < 4; ++m)
#pragma unroll
        for (int j = 0; j < 4; ++j) {
            int row = wr * 64 + m * 16 + lg * 4 + j;
            const float* Trow = Tg + (size_t)(n0 + row) * 128 + wc * 64 + lr;
#pragma unroll
            for (int n = 0; n < 4; ++n) {
                float tg = Trow[n * 16];
                if (tg != 0.0f) part += fabsf(acc[m][n][j] - tg);
            }
        }
    red[tid] = part;
    __syncthreads();
    for (int s = 128; s > 0; s >>= 1) {
        if (tid < s) red[tid] += red[tid + s];
        __syncthreads();
    }
    if (tid == 0) mpart[((size_t)t * NP + p) * 8 + nt] = red[0];
}

// ---------------------------------------------------------------------------
// K2 (fp32 fallback, verified round 1) — only used if ws_size too small
__global__ __launch_bounds__(256) void k_metrics(const float* __restrict__ G,
                                                 const float* __restrict__ sc,
                                                 float* __restrict__ mpart) {
    __shared__ float As[32 * 132];
    __shared__ float Bs[32 * 132];
    __shared__ float red[256];

    int nt = blockIdx.x, p = blockIdx.y, t = blockIdx.z;
    int tid = threadIdx.x;
    int tr = tid >> 4, tc = tid & 15;
    int n0 = nt * 128;

    const float* Gp = G + (size_t)p * NN + (size_t)n0 * 1024;
    const float* Xt = sc + (size_t)t * (N_NODE * NC);

    float acc[8][8];
#pragma unroll
    for (int a = 0; a < 8; ++a)
#pragma unroll
        for (int b = 0; b < 8; ++b) acc[a][b] = 0.f;

    for (int ko = 0; ko < 1024; ko += 32) {
#pragma unroll
        for (int it = 0; it < 4; ++it) {
            int fi = tid + it * 256;
            int r = fi >> 3, q = fi & 7;
            float4 g4 = *(const float4*)(Gp + (size_t)r * 1024 + ko + q * 4);
            As[(q * 4 + 0) * 132 + r] = g4.x;
            As[(q * 4 + 1) * 132 + r] = g4.y;
            As[(q * 4 + 2) * 132 + r] = g4.z;
            As[(q * 4 + 3) * 132 + r] = g4.w;
        }
#pragma unroll
        for (int it = 0; it < 4; ++it) {
            int fi = tid + it * 256;
            int kk = fi >> 5, cq = fi & 31;
            float4 x4 = *(const float4*)(Xt + (size_t)(ko + kk) * 128 + cq * 4);
            *(float4*)(&Bs[kk * 132 + cq * 4]) = x4;
        }
        __syncthreads();
#pragma unroll
        for (int kk = 0; kk < 32; ++kk) {
            float4 a0 = *(const float4*)(&As[kk * 132 + tr * 8]);
            float4 a1 = *(const float4*)(&As[kk * 132 + tr * 8 + 4]);
            float4 b0 = *(const float4*)(&Bs[kk * 132 + tc * 8]);
            float4 b1 = *(const float4*)(&Bs[kk * 132 + tc * 8 + 4]);
            float a[8] = {a0.x, a0.y, a0.z, a0.w, a1.x, a1.y, a1.z, a1.w};
            float b[8] = {b0.x, b0.y, b0.z, b0.w, b1.x, b1.y, b1.z, b1.w};
#pragma unroll
            for (int rr = 0; rr < 8; ++rr)
#pragma unroll
                for (int cc = 0; cc < 8; ++cc)
                    acc[rr][cc] = fmaf(a[rr], b[cc], acc[rr][cc]);
        }
        __syncthreads();
    }

    const float* Tg = sc + (size_t)(t + 1) * (N_NODE * NC);
    float part = 0.f;
#pragma unroll
    for (int rr = 0; rr < 8; ++rr) {
        int n = n0 + tr * 8 + rr;
#pragma unroll
        for (int cc = 0; cc < 8; ++cc) {
            int c = tc * 8 + cc;
            float tg = Tg[(size_t)n * 128 + c];
            if (tg != 0.0f) part += fabsf(acc[rr][cc] - tg);
        }
    }
    red[tid] = part;
    __syncthreads();
    for (int s = 128; s > 0; s >>= 1) {
        if (tid < s) red[tid] += red[tid + s];
        __syncthreads();
    }
    if (tid == 0) mpart[((size_t)t * NP + p) * 8 + nt] = red[0];
}

// ---------------------------------------------------------------------------
// K2b: per-t argmin over p (first index on ties)
__global__ void k_argmin(const float* __restrict__ mpart, int* __restrict__ idx) {
    int t = blockIdx.x;
    int tid = threadIdx.x;
    __shared__ float m[NP];
    if (tid < NP) {
        float s = 0.f;
        for (int nt = 0; nt < 8; ++nt) s += mpart[((size_t)t * NP + tid) * 8 + nt];
        m[tid] = s;
    }
    __syncthreads();
    if (tid == 0) {
        int best = 0; float bv = m[0];
        for (int p = 1; p < NP; ++p)
            if (m[p] < bv) { bv = m[p]; best = p; }
        idx[t] = best;
    }
}

// ---------------------------------------------------------------------------
__global__ void k_rowmean(const float* __restrict__ sc, float* __restrict__ meanv) {
    int r = blockIdx.x, c = threadIdx.x;
    __shared__ float red[128];
    red[c] = sc[(size_t)11 * (N_NODE * NC) + (size_t)r * 128 + c];
    __syncthreads();
    for (int s = 64; s > 0; s >>= 1) {
        if (c < s) red[c] += red[c + s];
        __syncthreads();
    }
    if (c == 0) meanv[r] = red[0] * (1.0f / 128.0f);
}

__global__ __launch_bounds__(256) void k_cov(const float* __restrict__ sc,
                                             const float* __restrict__ meanv,
                                             float* __restrict__ cov) {
    __shared__ float Ai[64 * 133];
    __shared__ float Bj[64 * 133];
    int bi = blockIdx.x, bj = blockIdx.y;
    int tid = threadIdx.x;
    int i0 = bi * 64, j0 = bj * 64;
    const float* L = sc + (size_t)11 * (N_NODE * NC);
#pragma unroll
    for (int it = 0; it < 8; ++it) {
        int fi = tid + it * 256;
        int r = fi >> 5, q = fi & 31;
        float4 a4 = *(const float4*)(L + (size_t)(i0 + r) * 128 + q * 4);
        float ma = meanv[i0 + r];
        Ai[r * 133 + q * 4 + 0] = a4.x - ma;
        Ai[r * 133 + q * 4 + 1] = a4.y - ma;
        Ai[r * 133 + q * 4 + 2] = a4.z - ma;
        Ai[r * 133 + q * 4 + 3] = a4.w - ma;
        float4 b4 = *(const float4*)(L + (size_t)(j0 + r) * 128 + q * 4);
        float mb = meanv[j0 + r];
        Bj[r * 133 + q * 4 + 0] = b4.x - mb;
        Bj[r * 133 + q * 4 + 1] = b4.y - mb;
        Bj[r * 133 + q * 4 + 2] = b4.z - mb;
        Bj[r * 133 + q * 4 + 3] = b4.w - mb;
    }
    __syncthreads();
    int ti = tid >> 4, tj = tid & 15;
    float acc[4][4];
#pragma unroll
    for (int a = 0; a < 4; ++a)
#pragma unroll
        for (int b = 0; b < 4; ++b) acc[a][b] = 0.f;
    for (int k = 0; k < 128; ++k) {
        float a[4], b[4];
#pragma unroll
        for (int rr = 0; rr < 4; ++rr) a[rr] = Ai[(ti * 4 + rr) * 133 + k];
#pragma unroll
        for (int cc = 0; cc < 4; ++cc) b[cc] = Bj[(tj * 4 + cc) * 133 + k];
#pragma unroll
        for (int rr = 0; rr < 4; ++rr)
#pragma unroll
            for (int cc = 0; cc < 4; ++cc)
                acc[rr][cc] = fmaf(a[rr], b[cc], acc[rr][cc]);
    }
#pragma unroll
    for (int rr = 0; rr < 4; ++rr)
#pragma unroll
        for (int cc = 0; cc < 4; ++cc)
            cov[(size_t)(i0 + ti * 4 + rr) * 1024 + j0 + tj * 4 + cc] =
                acc[rr][cc] * (1.0f / 127.0f);
}

// ---------------------------------------------------------------------------
__global__ __launch_bounds__(256) void k_gi_part(const float* __restrict__ Wih,
                                                 const float* __restrict__ G,
                                                 const float* __restrict__ cov,
                                                 const int* __restrict__ idx,
                                                 float* __restrict__ gipart) {
    int kc = blockIdx.x;
    int jg = blockIdx.y;
    int tid = threadIdx.x;
    int lane = tid & 63, wv = tid >> 6;
    int j0 = jg * 8 + wv * 2;

    const float* ctx[12];
#pragma unroll
    for (int t = 0; t < 11; ++t) ctx[t] = G + (size_t)idx[t] * NN;
    ctx[11] = cov;

    size_t kbase = (size_t)kc * 8192 + (size_t)lane * 4;
    const float* w0 = Wih + (size_t)j0 * NN;
    const float* w1 = Wih + (size_t)(j0 + 1) * NN;

    float acc[2][12];
#pragma unroll
    for (int j = 0; j < 2; ++j)
#pragma unroll
        for (int t = 0; t < 12; ++t) acc[j][t] = 0.f;

    for (int s = 0; s < 32; ++s) {
        size_t k = kbase + (size_t)s * 256;
        float4 wa = *(const float4*)(w0 + k);
        float4 wb = *(const float4*)(w1 + k);
#pragma unroll
        for (int t = 0; t < 12; ++t) {
            float4 x = *(const float4*)(ctx[t] + k);
            acc[0][t] += wa.x * x.x + wa.y * x.y + wa.z * x.z + wa.w * x.w;
            acc[1][t] += wb.x * x.x + wb.y * x.y + wb.z * x.z + wb.w * x.w;
        }
    }
#pragma unroll
    for (int j = 0; j < 2; ++j)
#pragma unroll
        for (int t = 0; t < 12; ++t) {
            float v = acc[j][t];
            for (int off = 32; off > 0; off >>= 1) v += __shfl_xor(v, off);
            if (lane == 0)
                gipart[((size_t)(j0 + j) * T_ALL + t) * 128 + kc] = v;
        }
}

__global__ void k_gi_reduce(const float* __restrict__ gipart,
                            const float* __restrict__ bih,
                            float* __restrict__ gi) {
    int o = blockIdx.x * 256 + threadIdx.x;
    if (o >= HJ * T_ALL) return;
    int j = o / T_ALL, t = o % T_ALL;
    float s = 0.f;
    for (int kc = 0; kc < 128; ++kc) s += gipart[(size_t)o * 128 + kc];
    gi[(size_t)t * HJ + j] = s + bih[j];
}

// ---------------------------------------------------------------------------
__global__ void k_gru(const float* __restrict__ gi, const float* __restrict__ Whh,
                      const float* __restrict__ bhh, int* __restrict__ idx) {
    __shared__ float h[HH], gh[HJ];
    int tid = threadIdx.x;
    if (tid < HH) h[tid] = 0.f;
    __syncthreads();
    for (int t = 0; t < T_ALL; ++t) {
        if (tid < HJ) {
            float s = bhh[tid];
            for (int k = 0; k < HH; ++k) s += Whh[tid * HH + k] * h[k];
            gh[tid] = s;
        }
        __syncthreads();
        if (tid < HH) {
            float gr = gi[t * HJ + tid];
            float gz = gi[t * HJ + 24 + tid];
            float gn = gi[t * HJ + 48 + tid];
            float r = 1.f / (1.f + expf(-(gr + gh[tid])));
            float z = 1.f / (1.f + expf(-(gz + gh[24 + tid])));
            float ng = tanhf(gn + r * gh[48 + tid]);
            h[tid] = (1.f - z) * ng + z * h[tid];
        }
        __syncthreads();
    }
    if (tid == 0) {
        int best = 0; float bv = h[0];
        for (int k = 1; k < HH; ++k)
            if (h[k] > bv) { bv = h[k]; best = k; }
        idx[11] = best;
    }
}

// ---------------------------------------------------------------------------
__global__ void k_gather(const float* __restrict__ G, const int* __restrict__ idx,
                         float4* __restrict__ out) {
    int i = blockIdx.x * 256 + threadIdx.x;
    int t = i >> 18;
    int r = i & 262143;
    const float4* src = (const float4*)(G + (size_t)idx[t] * NN);
    out[i] = src[r];
}

// ---------------------------------------------------------------------------
extern "C" void kernel_launch(void* const* d_in, const int* in_sizes, int n_in,
                              void* d_out, int out_size, void* d_ws, size_t ws_size,
                              hipStream_t stream) {
    const float* inp = (const float*)d_in[0];
    const float* G   = (const float*)d_in[1];
    const float* Wih = (const float*)d_in[2];
    const float* Whh = (const float*)d_in[3];
    const float* bih = (const float*)d_in[4];
    const float* bhh = (const float*)d_in[5];

    float* ws = (float*)d_ws;
    float* sc     = ws + WS_SC;
    float* cov    = ws + WS_COV;
    float* mpart  = ws + WS_MPART;
    int*   idx    = (int*)(ws + WS_IDX);
    float* meanv  = ws + WS_MEAN;
    float* gipart = ws + WS_GIPART;
    float* gi     = ws + WS_GI;

    char* wsb = (char*)d_ws;
    unsigned short* Ahi = (unsigned short*)(wsb + AB_BASE_BYTES);
    unsigned short* Bhi = (unsigned short*)(wsb + AB_BASE_BYTES + AHI_BYTES);

    bool use_mfma = (ws_size >= WS_NEED_BYTES);

    k_build_sc<<<128, 256, 0, stream>>>(inp, sc);
    if (use_mfma) {
        k_cvt_A<<<6144, 256, 0, stream>>>(G, Ahi);
        k_cvt_B<<<352, 256, 0, stream>>>(sc, Bhi);
        k_metrics_mfma<<<2112, 256, 0, stream>>>(Ahi, Bhi, sc, mpart);
    } else {
        k_metrics<<<dim3(8, NP, T1), 256, 0, stream>>>(G, sc, mpart);
    }
    k_argmin<<<T1, 32, 0, stream>>>(mpart, idx);
    k_rowmean<<<1024, 128, 0, stream>>>(sc, meanv);
    k_cov<<<dim3(16, 16), 256, 0, stream>>>(sc, meanv, cov);
    k_gi_part<<<dim3(128, 9), 256, 0, stream>>>(Wih, G, cov, idx, gipart);
    k_gi_reduce<<<4, 256, 0, stream>>>(gipart, bih, gi);
    k_gru<<<1, 128, 0, stream>>>(gi, Whh, bhh, idx);
    k_gather<<<12288, 256, 0, stream>>>(G, idx, (float4*)d_out);
}